// Round 10
// baseline (264.830 us; speedup 1.0000x reference)
//
#include <hip/hip_runtime.h>
#include <math.h>

#define NN 10000
#define EE 160000
#define GG 64
#define FIN 128
#define HH 256
#define ZW 512 /* HEADS*H */
#define RS 8   /* readout slices per graph */
#define MAXDEG 128

typedef unsigned short u16;
using bf16x8 = __attribute__((ext_vector_type(8))) short;
using f32x4 = __attribute__((ext_vector_type(4))) float;

__device__ inline u16 f2bf(float x) {
  union { float f; unsigned u; } v; v.f = x;
  unsigned r = v.u + 0x7FFF + ((v.u >> 16) & 1);
  return (u16)(r >> 16);
}
__device__ inline float bf2f(u16 x) {
  union { unsigned u; float f; } v; v.u = ((unsigned)x) << 16; return v.f;
}
__device__ inline float bflo(unsigned pair) {
  union { unsigned u; float f; } v; v.u = pair << 16; return v.f;
}
__device__ inline float bfhi(unsigned pair) {
  union { unsigned u; float f; } v; v.u = pair & 0xFFFF0000u; return v.f;
}

#define BM 128
#define BN 64
#define BK 64
#define LPAD 8

struct SmemGemm { u16 As[BM][BK + LPAD]; u16 Bs[BN][BK + LPAD]; };
struct SmemGatGemm { u16 A[2][64][BK + LPAD]; u16 B[2][64][BK + LPAD]; };
struct SmemFuseV2 {
  float al[4][2][MAXDEG];
  int   idx[4][MAXDEG];
  float inv[4][2];
  float mm[4][2];
};

// =================== preprocessing ===================

__global__ __launch_bounds__(256) void k_count_prep(
    const int* __restrict__ src, const int* __restrict__ dst, int* deg_src, int* deg_dst,
    const float* __restrict__ gcn1_W, u16* __restrict__ gcn1_Wt,
    const float* __restrict__ gcn2_W, u16* __restrict__ gcn2_Wt,
    const float* __restrict__ gcn3_W, u16* __restrict__ gcn3_Wt,
    const float* __restrict__ gat1_W, u16* __restrict__ gat1_Wt,
    const float* __restrict__ gat2_W, u16* __restrict__ gat2_Wt,
    const float* __restrict__ gat3_W, u16* __restrict__ gat3_Wt,
    const float* __restrict__ h, u16* __restrict__ h_bf,
    const float* __restrict__ al1, const float* __restrict__ ar1,
    const float* __restrict__ al2, const float* __restrict__ ar2,
    const float* __restrict__ al3, const float* __restrict__ ar3,
    float* __restrict__ wl1, float* __restrict__ wr1,
    float* __restrict__ wl2, float* __restrict__ wr2,
    float* __restrict__ wl3, float* __restrict__ wr3) {
  int bb = blockIdx.x, t = threadIdx.x;
  if (bb < 625) {
    int e = bb * 256 + t;
    if (e < EE) {
      atomicAdd(&deg_src[src[e]], 1);
      atomicAdd(&deg_dst[dst[e]], 1);
    }
    return;
  }
  int b = bb - 625;
  if (b < 1920) {
    const float* W; u16* Wt; int K, N, idx;
    if (b < 128)       { W = gcn1_W; Wt = gcn1_Wt; K = 128; N = 256; idx = b * 256 + t; }
    else if (b < 384)  { W = gcn2_W; Wt = gcn2_Wt; K = 256; N = 256; idx = (b - 128) * 256 + t; }
    else if (b < 640)  { W = gcn3_W; Wt = gcn3_Wt; K = 256; N = 256; idx = (b - 384) * 256 + t; }
    else if (b < 896)  { W = gat1_W; Wt = gat1_Wt; K = 128; N = 512; idx = (b - 640) * 256 + t; }
    else if (b < 1408) { W = gat2_W; Wt = gat2_Wt; K = 256; N = 512; idx = (b - 896) * 256 + t; }
    else               { W = gat3_W; Wt = gat3_Wt; K = 256; N = 512; idx = (b - 1408) * 256 + t; }
    int k = idx / N, n = idx - k * N;
    Wt[(size_t)n * K + k] = f2bf(W[idx]);
  } else if (b < 3170) {
    int idx = (b - 1920) * 256 + t;
    float4 v = *(const float4*)&h[(size_t)idx * 4];
    ushort4 o;
    o.x = f2bf(v.x); o.y = f2bf(v.y); o.z = f2bf(v.z); o.w = f2bf(v.w);
    *(ushort4*)&h_bf[(size_t)idx * 4] = o;
  } else {
    int jb = b - 3170;
    const float* W; const float* al; const float* ar; float* wl; float* wr; int K, i;
    if (jb == 0)      { W = gat1_W; al = al1; ar = ar1; wl = wl1; wr = wr1; K = 128; i = t; }
    else if (jb <= 2) { W = gat2_W; al = al2; ar = ar2; wl = wl2; wr = wr2; K = 256; i = (jb - 1) * 256 + t; }
    else              { W = gat3_W; al = al3; ar = ar3; wl = wl3; wr = wr3; K = 256; i = (jb - 3) * 256 + t; }
    int hh = i / K, k = i - hh * K;
    float sl = 0.f, sr = 0.f;
    for (int f = 0; f < HH; f++) {
      float wv = W[(size_t)k * ZW + hh * HH + f];
      sl += wv * al[hh * HH + f];
      sr += wv * ar[hh * HH + f];
    }
    wl[hh * K + k] = sl;
    wr[hh * K + k] = sr;
  }
}

// norms (blocks 0..9) + parallel single-pass scan (block 10)
__global__ __launch_bounds__(1024) void k_norms_scan(
    const int* __restrict__ deg_src, const int* __restrict__ deg_dst,
    const int* __restrict__ gid, float* dsrc, float* ddst, int* gstart, int* row_ptr) {
  if (blockIdx.x < 10) {
    int n = blockIdx.x * 1024 + threadIdx.x;
    if (n < NN) {
      int a = deg_src[n]; if (a < 1) a = 1;
      int b = deg_dst[n]; if (b < 1) b = 1;
      dsrc[n] = 1.0f / sqrtf((float)a);
      ddst[n] = 1.0f / sqrtf((float)b);
      if (n == 0) gstart[gid[0]] = 0;
      else if (gid[n] != gid[n - 1]) gstart[gid[n]] = n;
      if (n == NN - 1) gstart[GG] = NN;
    }
    return;
  }
  // single-pass parallel scan: thread t owns degrees [t*10, t*10+10)
  __shared__ int wsum[16];
  int t = threadIdx.x, lane = t & 63, wid = t >> 6;
  int base = t * 10;
  int loc[10];
  int s = 0;
#pragma unroll
  for (int i = 0; i < 10; i++) {
    int idx = base + i;
    int v = (idx < NN) ? deg_dst[idx] : 0;
    s += v;
    loc[i] = s;  // inclusive prefix within thread
  }
  int x = s;
#pragma unroll
  for (int off = 1; off < 64; off <<= 1) {
    int u = __shfl_up(x, off);
    if (lane >= off) x += u;
  }
  if (lane == 63) wsum[wid] = x;
  __syncthreads();
  if (wid == 0 && lane < 16) {
    int y = wsum[lane];
#pragma unroll
    for (int off = 1; off < 16; off <<= 1) {
      int u = __shfl_up(y, off, 16);
      if (lane >= off) y += u;
    }
    wsum[lane] = y;
  }
  __syncthreads();
  int woff = (wid > 0) ? wsum[wid - 1] : 0;
  int ex = woff + x - s;  // exclusive prefix of this thread's range
  if (t == 0) row_ptr[0] = 0;
#pragma unroll
  for (int i = 0; i < 10; i++) {
    int idx = base + i;
    if (idx < NN) row_ptr[idx + 1] = ex + loc[i];
  }
}

__global__ __launch_bounds__(64) void sort_rows_kernel(const int* __restrict__ row_ptr,
                                                       int* csr_src) {
  int n = blockIdx.x;
  int s0 = row_ptr[n];
  int L = row_ptr[n + 1] - s0;
  if (L <= 1) return;
  __shared__ int buf[512];
  if (L <= 512) {
    for (int i = threadIdx.x; i < L; i += 64) buf[i] = csr_src[s0 + i];
    __syncthreads();
    for (int i = threadIdx.x; i < L; i += 64) {
      int v = buf[i], r = 0;
      for (int j = 0; j < L; j++) {
        int u = buf[j];
        r += (u < v) || (u == v && j < i);
      }
      csr_src[s0 + r] = v;
    }
  } else if (threadIdx.x == 0) {
    for (int i = s0 + 1; i < s0 + L; i++) {
      int v = csr_src[i], j = i - 1;
      while (j >= s0 && csr_src[j] > v) { csr_src[j + 1] = csr_src[j]; j--; }
      csr_src[j + 1] = v;
    }
  }
}

// =================== device helpers ===================

__device__ inline void dev_gcn_agg(int n, int lane,
    const u16* __restrict__ xb, const float* __restrict__ dsrc, const float* __restrict__ ddst,
    const int* __restrict__ row_ptr, const int* __restrict__ csr_src,
    u16* __restrict__ out, int F) {
  int s0 = row_ptr[n], s1 = row_ptr[n + 1];
  float dd = ddst[n];
  if (F == 256) {
    int bf = lane * 4;
    float a0 = 0, a1 = 0, a2 = 0, a3 = 0;
    int e = s0;
    for (; e + 1 < s1; e += 2) {
      int sA = csr_src[e], sB = csr_src[e + 1];
      float wA = dsrc[sA], wB = dsrc[sB];
      uint2 vA = *(const uint2*)&xb[(size_t)sA * 256 + bf];
      uint2 vB = *(const uint2*)&xb[(size_t)sB * 256 + bf];
      a0 += wA * bflo(vA.x) + wB * bflo(vB.x);
      a1 += wA * bfhi(vA.x) + wB * bfhi(vB.x);
      a2 += wA * bflo(vA.y) + wB * bflo(vB.y);
      a3 += wA * bfhi(vA.y) + wB * bfhi(vB.y);
    }
    if (e < s1) {
      int s = csr_src[e];
      float w = dsrc[s];
      uint2 v = *(const uint2*)&xb[(size_t)s * 256 + bf];
      a0 += w * bflo(v.x); a1 += w * bfhi(v.x);
      a2 += w * bflo(v.y); a3 += w * bfhi(v.y);
    }
    ushort4 o;
    o.x = f2bf(a0 * dd); o.y = f2bf(a1 * dd); o.z = f2bf(a2 * dd); o.w = f2bf(a3 * dd);
    *(ushort4*)&out[(size_t)n * 256 + bf] = o;
  } else {  // F == 128
    int bf = lane * 2;
    float a0 = 0, a1 = 0;
    int e = s0;
    for (; e + 1 < s1; e += 2) {
      int sA = csr_src[e], sB = csr_src[e + 1];
      float wA = dsrc[sA], wB = dsrc[sB];
      unsigned vA = *(const unsigned*)&xb[(size_t)sA * 128 + bf];
      unsigned vB = *(const unsigned*)&xb[(size_t)sB * 128 + bf];
      a0 += wA * bflo(vA) + wB * bflo(vB);
      a1 += wA * bfhi(vA) + wB * bfhi(vB);
    }
    if (e < s1) {
      int s = csr_src[e];
      float w = dsrc[s];
      unsigned v = *(const unsigned*)&xb[(size_t)s * 128 + bf];
      a0 += w * bflo(v); a1 += w * bfhi(v);
    }
    ushort2 o;
    o.x = f2bf(a0 * dd); o.y = f2bf(a1 * dd);
    *(ushort2*)&out[(size_t)n * 128 + bf] = o;
  }
}

__device__ inline void dev_scores(int n, int lane, const float* __restrict__ x,
                                  const float* __restrict__ wl, const float* __restrict__ wr,
                                  float* __restrict__ asrc, float* __restrict__ adst, int K) {
  float a0 = 0, a1 = 0, b0 = 0, b1 = 0;
  for (int k = lane; k < K; k += 64) {
    float xv = x[(size_t)n * K + k];
    a0 += xv * wl[k];
    a1 += xv * wl[K + k];
    b0 += xv * wr[k];
    b1 += xv * wr[K + k];
  }
#pragma unroll
  for (int off = 32; off; off >>= 1) {
    a0 += __shfl_down(a0, off);
    a1 += __shfl_down(a1, off);
    b0 += __shfl_down(b0, off);
    b1 += __shfl_down(b1, off);
  }
  if (lane == 0) {
    asrc[n * 2 + 0] = a0; asrc[n * 2 + 1] = a1;
    adst[n * 2 + 0] = b0; adst[n * 2 + 1] = b1;
  }
}

__device__ inline void dev_scores_bf(int n, int lane, const u16* __restrict__ xb,
                                     const float* __restrict__ wl, const float* __restrict__ wr,
                                     float* __restrict__ asrc, float* __restrict__ adst) {
  float a0 = 0, a1 = 0, b0 = 0, b1 = 0;
#pragma unroll
  for (int idx = lane; idx < 128; idx += 64) {
    unsigned v = *(const unsigned*)&xb[(size_t)n * 256 + idx * 2];
    float lo = bflo(v), hi = bfhi(v);
    a0 += lo * wl[idx * 2] + hi * wl[idx * 2 + 1];
    a1 += lo * wl[256 + idx * 2] + hi * wl[256 + idx * 2 + 1];
    b0 += lo * wr[idx * 2] + hi * wr[idx * 2 + 1];
    b1 += lo * wr[256 + idx * 2] + hi * wr[256 + idx * 2 + 1];
  }
#pragma unroll
  for (int off = 32; off; off >>= 1) {
    a0 += __shfl_down(a0, off);
    a1 += __shfl_down(a1, off);
    b0 += __shfl_down(b0, off);
    b1 += __shfl_down(b1, off);
  }
  if (lane == 0) {
    asrc[n * 2 + 0] = a0; asrc[n * 2 + 1] = a1;
    adst[n * 2 + 0] = b0; adst[n * 2 + 1] = b1;
  }
}

// fused edge-softmax + x-space aggregation, 4 nodes/block, wave per node.
template<int F>
__device__ inline void dev_gatfuse_v3(int n0, int tid,
    const u16* __restrict__ xb,
    const float* __restrict__ asrc, const float* __restrict__ adst,
    const int* __restrict__ row_ptr, const int* __restrict__ csr_src,
    u16* __restrict__ gx, SmemFuseV2& sf) {
  int w = tid >> 6, lane = tid & 63;
  {
    int n = n0 + w;
    int s0 = row_ptr[n];
    int deg = row_ptr[n + 1] - s0;
    float2 an = *(const float2*)&adst[n * 2];
    float m0 = -INFINITY, m1 = -INFINITY;
    if (deg <= MAXDEG) {
      for (int i = lane; i < deg; i += 64) {
        int s = csr_src[s0 + i];
        sf.idx[w][i] = s;
        float2 as = *(const float2*)&asrc[s * 2];
        float e0 = as.x + an.x; e0 = (e0 > 0.f) ? e0 : 0.2f * e0;
        float e1 = as.y + an.y; e1 = (e1 > 0.f) ? e1 : 0.2f * e1;
        sf.al[w][0][i] = e0; sf.al[w][1][i] = e1;
        m0 = fmaxf(m0, e0); m1 = fmaxf(m1, e1);
      }
#pragma unroll
      for (int off = 32; off; off >>= 1) {
        m0 = fmaxf(m0, __shfl_xor(m0, off));
        m1 = fmaxf(m1, __shfl_xor(m1, off));
      }
      float t0 = 0.f, t1 = 0.f;
      for (int i = lane; i < deg; i += 64) {
        float w0 = __expf(sf.al[w][0][i] - m0);
        float w1 = __expf(sf.al[w][1][i] - m1);
        sf.al[w][0][i] = w0; sf.al[w][1][i] = w1;
        t0 += w0; t1 += w1;
      }
#pragma unroll
      for (int off = 32; off; off >>= 1) {
        t0 += __shfl_xor(t0, off);
        t1 += __shfl_xor(t1, off);
      }
      if (lane == 0) {
        sf.inv[w][0] = (t0 > 0.f) ? 1.f / t0 : 0.f;
        sf.inv[w][1] = (t1 > 0.f) ? 1.f / t1 : 0.f;
      }
    } else {
      for (int i = lane; i < deg; i += 64) {
        float2 as = *(const float2*)&asrc[csr_src[s0 + i] * 2];
        float e0 = as.x + an.x; e0 = (e0 > 0.f) ? e0 : 0.2f * e0;
        float e1 = as.y + an.y; e1 = (e1 > 0.f) ? e1 : 0.2f * e1;
        m0 = fmaxf(m0, e0); m1 = fmaxf(m1, e1);
      }
#pragma unroll
      for (int off = 32; off; off >>= 1) {
        m0 = fmaxf(m0, __shfl_xor(m0, off));
        m1 = fmaxf(m1, __shfl_xor(m1, off));
      }
      float t0 = 0.f, t1 = 0.f;
      for (int i = lane; i < deg; i += 64) {
        float2 as = *(const float2*)&asrc[csr_src[s0 + i] * 2];
        float e0 = as.x + an.x; e0 = (e0 > 0.f) ? e0 : 0.2f * e0;
        float e1 = as.y + an.y; e1 = (e1 > 0.f) ? e1 : 0.2f * e1;
        t0 += __expf(e0 - m0); t1 += __expf(e1 - m1);
      }
#pragma unroll
      for (int off = 32; off; off >>= 1) {
        t0 += __shfl_xor(t0, off);
        t1 += __shfl_xor(t1, off);
      }
      if (lane == 0) {
        sf.inv[w][0] = (t0 > 0.f) ? 1.f / t0 : 0.f;
        sf.inv[w][1] = (t1 > 0.f) ? 1.f / t1 : 0.f;
        sf.mm[w][0] = m0; sf.mm[w][1] = m1;
      }
    }
  }
  __syncthreads();
  int slot = w;
  int p = lane;
  int n = n0 + slot;
  int s0 = row_ptr[n];
  int deg = row_ptr[n + 1] - s0;
  float i0 = sf.inv[slot][0], i1 = sf.inv[slot][1];
  if (F == 256) {
    float a0[4] = {0, 0, 0, 0}, a1[4] = {0, 0, 0, 0};
    if (deg <= MAXDEG) {
      int i = 0;
      for (; i + 1 < deg; i += 2) {
        int sA = sf.idx[slot][i], sB = sf.idx[slot][i + 1];
        float wA0 = sf.al[slot][0][i] * i0, wA1 = sf.al[slot][1][i] * i1;
        float wB0 = sf.al[slot][0][i + 1] * i0, wB1 = sf.al[slot][1][i + 1] * i1;
        uint2 vA = *(const uint2*)&xb[(size_t)sA * 256 + p * 4];
        uint2 vB = *(const uint2*)&xb[(size_t)sB * 256 + p * 4];
        float fA[4] = {bflo(vA.x), bfhi(vA.x), bflo(vA.y), bfhi(vA.y)};
        float fB[4] = {bflo(vB.x), bfhi(vB.x), bflo(vB.y), bfhi(vB.y)};
#pragma unroll
        for (int j = 0; j < 4; j++) {
          a0[j] += wA0 * fA[j] + wB0 * fB[j];
          a1[j] += wA1 * fA[j] + wB1 * fB[j];
        }
      }
      if (i < deg) {
        int s = sf.idx[slot][i];
        float w0 = sf.al[slot][0][i] * i0, w1 = sf.al[slot][1][i] * i1;
        uint2 v = *(const uint2*)&xb[(size_t)s * 256 + p * 4];
        float fv[4] = {bflo(v.x), bfhi(v.x), bflo(v.y), bfhi(v.y)};
#pragma unroll
        for (int j = 0; j < 4; j++) {
          a0[j] += w0 * fv[j];
          a1[j] += w1 * fv[j];
        }
      }
    } else {
      float mh0 = sf.mm[slot][0], mh1 = sf.mm[slot][1];
      float2 an = *(const float2*)&adst[n * 2];
      for (int i = 0; i < deg; i++) {
        int s = csr_src[s0 + i];
        float2 as = *(const float2*)&asrc[s * 2];
        float e0 = as.x + an.x; e0 = (e0 > 0.f) ? e0 : 0.2f * e0;
        float e1 = as.y + an.y; e1 = (e1 > 0.f) ? e1 : 0.2f * e1;
        float w0 = __expf(e0 - mh0) * i0, w1 = __expf(e1 - mh1) * i1;
        uint2 v = *(const uint2*)&xb[(size_t)s * 256 + p * 4];
        float fv[4] = {bflo(v.x), bfhi(v.x), bflo(v.y), bfhi(v.y)};
#pragma unroll
        for (int j = 0; j < 4; j++) {
          a0[j] += w0 * fv[j];
          a1[j] += w1 * fv[j];
        }
      }
    }
    ushort4 o0, o1;
    o0.x = f2bf(a0[0]); o0.y = f2bf(a0[1]); o0.z = f2bf(a0[2]); o0.w = f2bf(a0[3]);
    o1.x = f2bf(a1[0]); o1.y = f2bf(a1[1]); o1.z = f2bf(a1[2]); o1.w = f2bf(a1[3]);
    *(ushort4*)&gx[(size_t)n * 512 + p * 4] = o0;
    *(ushort4*)&gx[(size_t)n * 512 + 256 + p * 4] = o1;
  } else {  // F == 128
    float a00 = 0.f, a01 = 0.f, a10 = 0.f, a11 = 0.f;
    if (deg <= MAXDEG) {
      int i = 0;
      for (; i + 1 < deg; i += 2) {
        int sA = sf.idx[slot][i], sB = sf.idx[slot][i + 1];
        float wA0 = sf.al[slot][0][i] * i0, wA1 = sf.al[slot][1][i] * i1;
        float wB0 = sf.al[slot][0][i + 1] * i0, wB1 = sf.al[slot][1][i + 1] * i1;
        unsigned vA = *(const unsigned*)&xb[(size_t)sA * 128 + p * 2];
        unsigned vB = *(const unsigned*)&xb[(size_t)sB * 128 + p * 2];
        float lA = bflo(vA), hA = bfhi(vA), lB = bflo(vB), hB = bfhi(vB);
        a00 += wA0 * lA + wB0 * lB; a01 += wA0 * hA + wB0 * hB;
        a10 += wA1 * lA + wB1 * lB; a11 += wA1 * hA + wB1 * hB;
      }
      if (i < deg) {
        int s = sf.idx[slot][i];
        float w0 = sf.al[slot][0][i] * i0, w1 = sf.al[slot][1][i] * i1;
        unsigned v = *(const unsigned*)&xb[(size_t)s * 128 + p * 2];
        float lo = bflo(v), hi = bfhi(v);
        a00 += w0 * lo; a01 += w0 * hi;
        a10 += w1 * lo; a11 += w1 * hi;
      }
    } else {
      float mh0 = sf.mm[slot][0], mh1 = sf.mm[slot][1];
      float2 an = *(const float2*)&adst[n * 2];
      for (int i = 0; i < deg; i++) {
        int s = csr_src[s0 + i];
        float2 as = *(const float2*)&asrc[s * 2];
        float e0 = as.x + an.x; e0 = (e0 > 0.f) ? e0 : 0.2f * e0;
        float e1 = as.y + an.y; e1 = (e1 > 0.f) ? e1 : 0.2f * e1;
        float w0 = __expf(e0 - mh0) * i0, w1 = __expf(e1 - mh1) * i1;
        unsigned v = *(const unsigned*)&xb[(size_t)s * 128 + p * 2];
        float lo = bflo(v), hi = bfhi(v);
        a00 += w0 * lo; a01 += w0 * hi;
        a10 += w1 * lo; a11 += w1 * hi;
      }
    }
    ushort2 o0; o0.x = f2bf(a00); o0.y = f2bf(a01);
    ushort2 o1; o1.x = f2bf(a10); o1.y = f2bf(a11);
    *(ushort2*)&gx[(size_t)n * 256 + p * 2] = o0;
    *(ushort2*)&gx[(size_t)n * 256 + 128 + p * 2] = o1;
  }
}

__device__ inline void dev_gemm(const u16* __restrict__ A, const u16* __restrict__ Wt,
                                const float* __restrict__ bias, u16* __restrict__ Cb,
                                int K, int Nc, int relu, int bx, int by, int tid,
                                SmemGemm& sm) {
  int lane = tid & 63;
  int wid = tid >> 6;
  int wm = wid & 1, wn = wid >> 1;
  int l15 = lane & 15, lg = lane >> 4;
  int row0 = bx * BM;
  int col0 = by * BN;
  f32x4 acc[4][2] = {};
  for (int k0 = 0; k0 < K; k0 += BK) {
#pragma unroll
    for (int p = 0; p < 4; p++) {
      int c = p * 256 + tid;
      int r = c >> 3, k8 = c & 7;
      uint4 v = make_uint4(0, 0, 0, 0);
      int gr = row0 + r;
      if (gr < NN) v = *(const uint4*)&A[(size_t)gr * K + k0 + k8 * 8];
      *(uint4*)&sm.As[r][k8 * 8] = v;
    }
#pragma unroll
    for (int p = 0; p < 2; p++) {
      int c = p * 256 + tid;
      int r = c >> 3, k8 = c & 7;
      uint4 v = *(const uint4*)&Wt[(size_t)(col0 + r) * K + k0 + k8 * 8];
      *(uint4*)&sm.Bs[r][k8 * 8] = v;
    }
    __syncthreads();
#pragma unroll
    for (int ks = 0; ks < BK; ks += 32) {
      bf16x8 afr[4], bfr[2];
#pragma unroll
      for (int m = 0; m < 4; m++)
        afr[m] = *(const bf16x8*)&sm.As[wm * 64 + m * 16 + l15][ks + lg * 8];
#pragma unroll
      for (int nn = 0; nn < 2; nn++)
        bfr[nn] = *(const bf16x8*)&sm.Bs[wn * 32 + nn * 16 + l15][ks + lg * 8];
#pragma unroll
      for (int m = 0; m < 4; m++)
#pragma unroll
        for (int nn = 0; nn < 2; nn++)
          acc[m][nn] = __builtin_amdgcn_mfma_f32_16x16x32_bf16(afr[m], bfr[nn], acc[m][nn], 0, 0, 0);
    }
    __syncthreads();
  }
#pragma unroll
  for (int m = 0; m < 4; m++) {
#pragma unroll
    for (int nn = 0; nn < 2; nn++) {
      int gc = col0 + wn * 32 + nn * 16 + l15;
      float bv = bias ? bias[gc] : 0.f;
#pragma unroll
      for (int j = 0; j < 4; j++) {
        int gr = row0 + wm * 64 + m * 16 + lg * 4 + j;
        if (gr < NN) {
          float v = acc[m][nn][j] + bv;
          if (relu) v = fmaxf(v, 0.f);
          Cb[(size_t)gr * Nc + gc] = f2bf(v);
        }
      }
    }
  }
}

__device__ inline void dev_gat_gemm(const u16* __restrict__ gx, const u16* __restrict__ Wt,
                                    const float* __restrict__ bias, u16* __restrict__ gb,
                                    int K, int bx, int by, int tid, SmemGatGemm& sm) {
  int lane = tid & 63;
  int wid = tid >> 6;
  int wm = wid & 1, wn = wid >> 1;
  int l15 = lane & 15, lg = lane >> 4;
  int row0 = bx * 64;
  int col0 = by * 64;
  int str = 2 * K;
  f32x4 acc[2][2][2] = {};
  for (int k0 = 0; k0 < K; k0 += BK) {
#pragma unroll
    for (int hh = 0; hh < 2; hh++) {
#pragma unroll
      for (int p = 0; p < 2; p++) {
        int c = p * 256 + tid;
        int r = c >> 3, k8 = c & 7;
        int gr = row0 + r;
        uint4 v = make_uint4(0, 0, 0, 0);
        if (gr < NN) v = *(const uint4*)&gx[(size_t)gr * str + hh * K + k0 + k8 * 8];
        *(uint4*)&sm.A[hh][r][k8 * 8] = v;
      }
#pragma unroll
      for (int p = 0; p < 2; p++) {
        int c = p * 256 + tid;
        int r = c >> 3, k8 = c & 7;
        uint4 v = *(const uint4*)&Wt[(size_t)(hh * 256 + col0 + r) * K + k0 + k8 * 8];
        *(uint4*)&sm.B[hh][r][k8 * 8] = v;
      }
    }
    __syncthreads();
#pragma unroll
    for (int ks = 0; ks < BK; ks += 32) {
      bf16x8 af[2][2], bf_[2][2];
#pragma unroll
      for (int hh = 0; hh < 2; hh++) {
#pragma unroll
        for (int m = 0; m < 2; m++)
          af[hh][m] = *(const bf16x8*)&sm.A[hh][wm * 32 + m * 16 + l15][ks + lg * 8];
#pragma unroll
        for (int nn = 0; nn < 2; nn++)
          bf_[hh][nn] = *(const bf16x8*)&sm.B[hh][wn * 32 + nn * 16 + l15][ks + lg * 8];
      }
#pragma unroll
      for (int hh = 0; hh < 2; hh++)
#pragma unroll
        for (int m = 0; m < 2; m++)
#pragma unroll
          for (int nn = 0; nn < 2; nn++)
            acc[hh][m][nn] = __builtin_amdgcn_mfma_f32_16x16x32_bf16(af[hh][m], bf_[hh][nn], acc[hh][m][nn], 0, 0, 0);
    }
    __syncthreads();
  }
#pragma unroll
  for (int m = 0; m < 2; m++) {
#pragma unroll
    for (int nn = 0; nn < 2; nn++) {
      int gc = col0 + wn * 32 + nn * 16 + l15;
      float bv0 = bias[gc], bv1 = bias[256 + gc];
#pragma unroll
      for (int j = 0; j < 4; j++) {
        int gr = row0 + wm * 32 + m * 16 + lg * 4 + j;
        if (gr < NN) {
          float r0 = fmaxf(acc[0][m][nn][j] + bv0, 0.f);
          float r1 = fmaxf(acc[1][m][nn][j] + bv1, 0.f);
          gb[(size_t)gr * 256 + gc] = f2bf(0.5f * (r0 + r1));
        }
      }
    }
  }
}

__device__ inline void dev_stage1(const u16* __restrict__ x, int l, int g, int s, int f,
                                  const int* __restrict__ gstart, float* __restrict__ partial) {
  int n0 = gstart[g], n1 = gstart[g + 1];
  int cnt = n1 - n0;
  int chunk = (cnt + RS - 1) / RS;
  int a = n0 + s * chunk;
  int bnd = a + chunk; if (bnd > n1) bnd = n1;
  float sum = 0.f, mx = -INFINITY;
  for (int n = a; n < bnd; n++) {
    float v = bf2f(x[(size_t)n * HH + f]);
    sum += v;
    mx = fmaxf(mx, v);
  }
  size_t base = ((size_t)l * GG * RS + g * RS + s) * 2 * HH;
  partial[base + f] = sum;
  partial[base + HH + f] = mx;
}

__device__ inline float dev_stage2_val(const float* __restrict__ partial, int l, int g, int tt,
                                       const int* __restrict__ gstart) {
  int f = tt & 255, ismax = tt >> 8;
  size_t base = ((size_t)l * GG * RS + g * RS) * 2 * HH;
  if (!ismax) {
    float s = 0.f;
    for (int k = 0; k < RS; k++) s += partial[base + (size_t)k * 2 * HH + f];
    return s / (float)(gstart[g + 1] - gstart[g]);
  } else {
    float m = -INFINITY;
    for (int k = 0; k < RS; k++) m = fmaxf(m, partial[base + (size_t)k * 2 * HH + HH + f]);
    return m;
  }
}

// =================== stage kernels ===================

// fill_csr [0,625) + scores1 (fp32 h) [625,3125)
__global__ __launch_bounds__(256) void k_fill_scores(
    const int* __restrict__ src, const int* __restrict__ dst,
    const int* __restrict__ row_ptr, int* fill, int* csr_src,
    const float* __restrict__ h, const float* __restrict__ wl1, const float* __restrict__ wr1,
    float* __restrict__ asrc, float* __restrict__ adst) {
  int b = blockIdx.x, t = threadIdx.x;
  if (b < 625) {
    int e = b * 256 + t;
    if (e < EE) {
      int d = dst[e];
      int p = atomicAdd(&fill[d], 1);
      csr_src[row_ptr[d] + p] = src[e];
    }
  } else {
    int n = (b - 625) * 4 + (t >> 6);
    if (n < NN) dev_scores(n, t & 63, h, wl1, wr1, asrc, adst, FIN);
  }
}

// gcn_agg1(F=128) [0,2500) + gatfuse1<128> [2500,5000)
__global__ __launch_bounds__(256) void k_a1(
    const u16* __restrict__ h_bf, const float* __restrict__ dsrc, const float* __restrict__ ddst,
    const int* __restrict__ row_ptr, const int* __restrict__ csr_src,
    u16* __restrict__ zagg, const float* __restrict__ asrc, const float* __restrict__ adst,
    u16* __restrict__ gx) {
  __shared__ SmemFuseV2 sf;
  int b = blockIdx.x, t = threadIdx.x;
  if (b < 2500) {
    int n = b * 4 + (t >> 6);
    dev_gcn_agg(n, t & 63, h_bf, dsrc, ddst, row_ptr, csr_src, zagg, FIN);
  } else {
    dev_gatfuse_v3<128>((b - 2500) * 4, t, h_bf, asrc, adst, row_ptr, csr_src, gx, sf);
  }
}

// gcn GEMM [0,316) + gat GEMM [316,944)
__global__ __launch_bounds__(256) void k_b(
    const u16* __restrict__ zagg, const u16* __restrict__ gcn_Wt, const float* __restrict__ gcn_b,
    u16* __restrict__ ab_out, int Kg,
    const u16* __restrict__ gx, const u16* __restrict__ gat_Wt, const float* __restrict__ gat_b,
    u16* __restrict__ gb_out, int Ka) {
  __shared__ union { SmemGemm g; SmemGatGemm gg; } sm;
  int b = blockIdx.x, t = threadIdx.x;
  if (b < 316) {
    dev_gemm(zagg, gcn_Wt, gcn_b, ab_out, Kg, HH, 1, b % 79, b / 79, t, sm.g);
  } else {
    int i = b - 316;
    dev_gat_gemm(gx, gat_Wt, gat_b, gb_out, Ka, i / 4, i % 4, t, sm.gg);
  }
}

// scores only (2500 blocks, 4 nodes each)
__global__ __launch_bounds__(256) void k_sc(
    const u16* __restrict__ gb_prev, const float* __restrict__ wl, const float* __restrict__ wr,
    float* __restrict__ asrc, float* __restrict__ adst) {
  int n = blockIdx.x * 4 + (threadIdx.x >> 6);
  dev_scores_bf(n, threadIdx.x & 63, gb_prev, wl, wr, asrc, adst);
}

// gcn_agg(F=256) [0,2500) + gatfuse<256> [2500,5000)
__global__ __launch_bounds__(256) void k_af(
    const u16* __restrict__ ab_prev, const float* __restrict__ dsrc, const float* __restrict__ ddst,
    const int* __restrict__ row_ptr, const int* __restrict__ csr_src, u16* __restrict__ zagg,
    const u16* __restrict__ gb_prev, const float* __restrict__ asrc, const float* __restrict__ adst,
    u16* __restrict__ gx) {
  __shared__ SmemFuseV2 sf;
  int b = blockIdx.x, t = threadIdx.x;
  if (b < 2500) {
    int n = b * 4 + (t >> 6);
    dev_gcn_agg(n, t & 63, ab_prev, dsrc, ddst, row_ptr, csr_src, zagg, HH);
  } else {
    dev_gatfuse_v3<256>((b - 2500) * 4, t, gb_prev, asrc, adst, row_ptr, csr_src, gx, sf);
  }
}

// layer3: gcn_agg [0,2500) + gatfuse<256> [2500,5000) + stage1(ab1->l0,ab2->l1,gb2->l3) [5000,6536)
struct Acts3 { const u16* a[3]; };
__global__ __launch_bounds__(256) void k_af3(
    const u16* __restrict__ ab_prev, const float* __restrict__ dsrc, const float* __restrict__ ddst,
    const int* __restrict__ row_ptr, const int* __restrict__ csr_src, u16* __restrict__ zagg,
    const u16* __restrict__ gb_prev, const float* __restrict__ asrc, const float* __restrict__ adst,
    u16* __restrict__ gx,
    Acts3 acts, const int* __restrict__ gstart, float* __restrict__ partial) {
  __shared__ SmemFuseV2 sf;
  int b = blockIdx.x, t = threadIdx.x;
  if (b < 2500) {
    int n = b * 4 + (t >> 6);
    dev_gcn_agg(n, t & 63, ab_prev, dsrc, ddst, row_ptr, csr_src, zagg, HH);
  } else if (b < 5000) {
    dev_gatfuse_v3<256>((b - 2500) * 4, t, gb_prev, asrc, adst, row_ptr, csr_src, gx, sf);
  } else {
    int i = b - 5000;
    int li = i >> 9, rem = i & 511;
    int lmap[3] = {0, 1, 3};
    dev_stage1(acts.a[li], lmap[li], rem >> 3, rem & 7, t, gstart, partial);
  }
}

// fc head: stage2 for l0,l1,l3 from partial + DIRECT readout of ab3/gb3 + assemble + fc
__global__ __launch_bounds__(512) void k_fc(
    const float* __restrict__ partial, const int* __restrict__ gstart,
    const u16* __restrict__ ab3, const u16* __restrict__ gb3,
    const float* __restrict__ W1, const float* __restrict__ b1,
    const float* __restrict__ W2, const float* __restrict__ b2, float* __restrict__ out) {
  int g = blockIdx.x;
  int t = threadIdx.x;
  __shared__ float row[1024];
  __shared__ float f1[128];
  __shared__ float r2s[512];  // [avg(ab3) | max(ab3)]
  __shared__ float r4s[512];  // [avg(gb3) | max(gb3)]
  {
    // direct per-graph readout: threads 0..255 -> ab3 feat t; 256..511 -> gb3 feat t-256
    const u16* arr = (t < 256) ? ab3 : gb3;
    int f = t & 255;
    int n0 = gstart[g], n1 = gstart[g + 1];
    float sum = 0.f, mx = -INFINITY;
    for (int n = n0; n < n1; n++) {
      float v = bf2f(arr[(size_t)n * HH + f]);
      sum += v;
      mx = fmaxf(mx, v);
    }
    float avg = sum / (float)(n1 - n0);
    if (t < 256) { r2s[f] = avg; r2s[256 + f] = mx; }
    else         { r4s[f] = avg; r4s[256 + f] = mx; }
  }
  __syncthreads();
  {
    int c = t;
    float s0 = dev_stage2_val(partial, 0, g, c, gstart);
    float s1 = dev_stage2_val(partial, 1, g, c, gstart);
    float s3v = dev_stage2_val(partial, 3, g, c, gstart);
    float spec = s0 + s1 + r2s[c];
    float last = (c < 256) ? s3v : r4s[c];
    float spat = s0 + s3v + last;
    row[c] = spec;
    row[512 + c] = spat;
  }
  __syncthreads();
  if (t < 128) {
    float acc = b1[t];
    for (int k = 0; k < 1024; k++) acc += row[k] * W1[k * 128 + t];
    f1[t] = fmaxf(acc, 0.f);
  }
  __syncthreads();
  if (t < 2) {
    float a = b2[t];
    for (int k = 0; k < 128; k++) a += f1[k] * W2[k * 2 + t];
    out[g * 2 + t] = 1.f / (1.f + expf(-a));
  }
}

extern "C" void kernel_launch(void* const* d_in, const int* in_sizes, int n_in,
                              void* d_out, int out_size, void* d_ws, size_t ws_size,
                              hipStream_t stream) {
  const float* h      = (const float*)d_in[0];
  const int*   src    = (const int*)d_in[1];
  const int*   dst    = (const int*)d_in[2];
  const int*   gid    = (const int*)d_in[3];
  const float* gcn1_W = (const float*)d_in[4];  const float* gcn1_b = (const float*)d_in[5];
  const float* gcn2_W = (const float*)d_in[6];  const float* gcn2_b = (const float*)d_in[7];
  const float* gcn3_W = (const float*)d_in[8];  const float* gcn3_b = (const float*)d_in[9];
  const float* gat1_W = (const float*)d_in[10]; const float* gat1_al = (const float*)d_in[11];
  const float* gat1_ar= (const float*)d_in[12]; const float* gat1_b = (const float*)d_in[13];
  const float* gat2_W = (const float*)d_in[14]; const float* gat2_al = (const float*)d_in[15];
  const float* gat2_ar= (const float*)d_in[16]; const float* gat2_b = (const float*)d_in[17];
  const float* gat3_W = (const float*)d_in[18]; const float* gat3_al = (const float*)d_in[19];
  const float* gat3_ar= (const float*)d_in[20]; const float* gat3_b = (const float*)d_in[21];
  const float* fc1_W  = (const float*)d_in[22]; const float* fc1_b = (const float*)d_in[23];
  const float* fc2_W  = (const float*)d_in[24]; const float* fc2_b = (const float*)d_in[25];

  char* ws = (char*)d_ws;
  size_t off = 0;
  auto alloc = [&](size_t bytes) -> void* {
    void* p = ws + off;
    off += (bytes + 255) & ~(size_t)255;
    return p;
  };
  u16*   gx      = (u16*)alloc((size_t)NN * ZW * 2);
  u16*   Zagg    = (u16*)alloc((size_t)NN * HH * 2);
  u16*   h_bf    = (u16*)alloc((size_t)NN * FIN * 2);
  u16*   ab1     = (u16*)alloc((size_t)NN * HH * 2);
  u16*   ab2     = (u16*)alloc((size_t)NN * HH * 2);
  u16*   ab3     = (u16*)alloc((size_t)NN * HH * 2);
  u16*   gb1     = (u16*)alloc((size_t)NN * HH * 2);
  u16*   gb2     = (u16*)alloc((size_t)NN * HH * 2);
  u16*   gb3     = (u16*)alloc((size_t)NN * HH * 2);
  int*   row_ptr = (int*)alloc((NN + 1) * 4);
  int*   csr_src = (int*)alloc((size_t)EE * 4);
  int*   meta    = (int*)alloc((size_t)3 * NN * 4);
  int*   deg_src = meta;
  int*   deg_dst = meta + NN;
  int*   fill    = meta + 2 * NN;
  float* dsrc    = (float*)alloc(NN * 4);
  float* ddst    = (float*)alloc(NN * 4);
  int*   gstart  = (int*)alloc((GG + 1) * 4);
  float* asrc    = (float*)alloc(NN * 2 * 4);
  float* adst    = (float*)alloc(NN * 2 * 4);
  float* wl1     = (float*)alloc(2 * FIN * 4);
  float* wr1     = (float*)alloc(2 * FIN * 4);
  float* wl2     = (float*)alloc(2 * HH * 4);
  float* wr2     = (float*)alloc(2 * HH * 4);
  float* wl3     = (float*)alloc(2 * HH * 4);
  float* wr3     = (float*)alloc(2 * HH * 4);
  float* partial = (float*)alloc((size_t)5 * GG * RS * 2 * HH * 4);
  u16* gcn1_Wt = (u16*)alloc((size_t)FIN * HH * 2);
  u16* gcn2_Wt = (u16*)alloc((size_t)HH * HH * 2);
  u16* gcn3_Wt = (u16*)alloc((size_t)HH * HH * 2);
  u16* gat1_Wt = (u16*)alloc((size_t)FIN * ZW * 2);
  u16* gat2_Wt = (u16*)alloc((size_t)HH * ZW * 2);
  u16* gat3_Wt = (u16*)alloc((size_t)HH * ZW * 2);

  hipMemsetAsync(meta, 0, (size_t)3 * NN * 4, stream);
  k_count_prep<<<3800, 256, 0, stream>>>(
      src, dst, deg_src, deg_dst,
      gcn1_W, gcn1_Wt, gcn2_W, gcn2_Wt, gcn3_W, gcn3_Wt,
      gat1_W, gat1_Wt, gat2_W, gat2_Wt, gat3_W, gat3_Wt,
      h, h_bf,
      gat1_al, gat1_ar, gat2_al, gat2_ar, gat3_al, gat3_ar,
      wl1, wr1, wl2, wr2, wl3, wr3);
  k_norms_scan<<<11, 1024, 0, stream>>>(deg_src, deg_dst, gid, dsrc, ddst, gstart, row_ptr);
  k_fill_scores<<<3125, 256, 0, stream>>>(src, dst, row_ptr, fill, csr_src,
                                          h, wl1, wr1, asrc, adst);
  sort_rows_kernel<<<NN, 64, 0, stream>>>(row_ptr, csr_src);

  // layer 1
  k_a1<<<5000, 256, 0, stream>>>(h_bf, dsrc, ddst, row_ptr, csr_src, Zagg, asrc, adst, gx);
  k_b<<<944, 256, 0, stream>>>(Zagg, gcn1_Wt, gcn1_b, ab1, FIN,
                               gx, gat1_Wt, gat1_b, gb1, FIN);
  // layer 2
  k_sc<<<2500, 256, 0, stream>>>(gb1, wl2, wr2, asrc, adst);
  k_af<<<5000, 256, 0, stream>>>(ab1, dsrc, ddst, row_ptr, csr_src, Zagg,
                                 gb1, asrc, adst, gx);
  k_b<<<944, 256, 0, stream>>>(Zagg, gcn2_Wt, gcn2_b, ab2, HH,
                               gx, gat2_Wt, gat2_b, gb2, HH);
  // layer 3
  k_sc<<<2500, 256, 0, stream>>>(gb2, wl3, wr3, asrc, adst);
  Acts3 acts; acts.a[0] = ab1; acts.a[1] = ab2; acts.a[2] = gb2;
  k_af3<<<6536, 256, 0, stream>>>(ab2, dsrc, ddst, row_ptr, csr_src, Zagg,
                                  gb2, asrc, adst, gx,
                                  acts, gstart, partial);
  k_b<<<944, 256, 0, stream>>>(Zagg, gcn3_Wt, gcn3_b, ab3, HH,
                               gx, gat3_Wt, gat3_b, gb3, HH);
  // head (readouts of ab3/gb3 fused in)
  k_fc<<<GG, 512, 0, stream>>>(partial, gstart, ab3, gb3,
                               fc1_W, fc1_b, fc2_W, fc2_b, (float*)d_out);
}

// Round 11
// 237.404 us; speedup vs baseline: 1.1155x; 1.1155x over previous
//
#include <hip/hip_runtime.h>
#include <math.h>

#define NN 10000
#define EE 160000
#define GG 64
#define FIN 128
#define HH 256
#define ZW 512 /* HEADS*H */
#define RS 8   /* readout slices per graph */
#define MAXDEG 128

typedef unsigned short u16;
using bf16x8 = __attribute__((ext_vector_type(8))) short;
using f32x4 = __attribute__((ext_vector_type(4))) float;

__device__ inline u16 f2bf(float x) {
  union { float f; unsigned u; } v; v.f = x;
  unsigned r = v.u + 0x7FFF + ((v.u >> 16) & 1);
  return (u16)(r >> 16);
}
__device__ inline float bf2f(u16 x) {
  union { unsigned u; float f; } v; v.u = ((unsigned)x) << 16; return v.f;
}
__device__ inline float bflo(unsigned pair) {
  union { unsigned u; float f; } v; v.u = pair << 16; return v.f;
}
__device__ inline float bfhi(unsigned pair) {
  union { unsigned u; float f; } v; v.u = pair & 0xFFFF0000u; return v.f;
}

#define BM 128
#define BN 64
#define BK 64
#define LPAD 8

struct SmemGemm { u16 As[BM][BK + LPAD]; u16 Bs[BN][BK + LPAD]; };
struct SmemGatGemm { u16 A[2][64][BK + LPAD]; u16 B[2][64][BK + LPAD]; };
struct SmemFuseV2 {
  float al[4][2][MAXDEG];
  int   idx[4][MAXDEG];
  float inv[4][2];
  float mm[4][2];
};

// =================== preprocessing ===================

__global__ __launch_bounds__(256) void k_count_prep(
    const int* __restrict__ src, const int* __restrict__ dst, int* deg_src, int* deg_dst,
    const float* __restrict__ gcn1_W, u16* __restrict__ gcn1_Wt,
    const float* __restrict__ gcn2_W, u16* __restrict__ gcn2_Wt,
    const float* __restrict__ gcn3_W, u16* __restrict__ gcn3_Wt,
    const float* __restrict__ gat1_W, u16* __restrict__ gat1_Wt,
    const float* __restrict__ gat2_W, u16* __restrict__ gat2_Wt,
    const float* __restrict__ gat3_W, u16* __restrict__ gat3_Wt,
    const float* __restrict__ h, u16* __restrict__ h_bf,
    const float* __restrict__ al1, const float* __restrict__ ar1,
    const float* __restrict__ al2, const float* __restrict__ ar2,
    const float* __restrict__ al3, const float* __restrict__ ar3,
    float* __restrict__ wl1, float* __restrict__ wr1,
    float* __restrict__ wl2, float* __restrict__ wr2,
    float* __restrict__ wl3, float* __restrict__ wr3) {
  int bb = blockIdx.x, t = threadIdx.x;
  if (bb < 625) {
    int e = bb * 256 + t;
    if (e < EE) {
      atomicAdd(&deg_src[src[e]], 1);
      atomicAdd(&deg_dst[dst[e]], 1);
    }
    return;
  }
  int b = bb - 625;
  if (b < 1920) {
    const float* W; u16* Wt; int K, N, idx;
    if (b < 128)       { W = gcn1_W; Wt = gcn1_Wt; K = 128; N = 256; idx = b * 256 + t; }
    else if (b < 384)  { W = gcn2_W; Wt = gcn2_Wt; K = 256; N = 256; idx = (b - 128) * 256 + t; }
    else if (b < 640)  { W = gcn3_W; Wt = gcn3_Wt; K = 256; N = 256; idx = (b - 384) * 256 + t; }
    else if (b < 896)  { W = gat1_W; Wt = gat1_Wt; K = 128; N = 512; idx = (b - 640) * 256 + t; }
    else if (b < 1408) { W = gat2_W; Wt = gat2_Wt; K = 256; N = 512; idx = (b - 896) * 256 + t; }
    else               { W = gat3_W; Wt = gat3_Wt; K = 256; N = 512; idx = (b - 1408) * 256 + t; }
    int k = idx / N, n = idx - k * N;
    Wt[(size_t)n * K + k] = f2bf(W[idx]);
  } else if (b < 3170) {
    int idx = (b - 1920) * 256 + t;
    float4 v = *(const float4*)&h[(size_t)idx * 4];
    ushort4 o;
    o.x = f2bf(v.x); o.y = f2bf(v.y); o.z = f2bf(v.z); o.w = f2bf(v.w);
    *(ushort4*)&h_bf[(size_t)idx * 4] = o;
  } else {
    int jb = b - 3170;
    const float* W; const float* al; const float* ar; float* wl; float* wr; int K, i;
    if (jb == 0)      { W = gat1_W; al = al1; ar = ar1; wl = wl1; wr = wr1; K = 128; i = t; }
    else if (jb <= 2) { W = gat2_W; al = al2; ar = ar2; wl = wl2; wr = wr2; K = 256; i = (jb - 1) * 256 + t; }
    else              { W = gat3_W; al = al3; ar = ar3; wl = wl3; wr = wr3; K = 256; i = (jb - 3) * 256 + t; }
    int hh = i / K, k = i - hh * K;
    float sl = 0.f, sr = 0.f;
    for (int f = 0; f < HH; f++) {
      float wv = W[(size_t)k * ZW + hh * HH + f];
      sl += wv * al[hh * HH + f];
      sr += wv * ar[hh * HH + f];
    }
    wl[hh * K + k] = sl;
    wr[hh * K + k] = sr;
  }
}

// norms (blocks 0..9) + parallel single-pass scan (block 10)
__global__ __launch_bounds__(1024) void k_norms_scan(
    const int* __restrict__ deg_src, const int* __restrict__ deg_dst,
    const int* __restrict__ gid, float* dsrc, float* ddst, int* gstart, int* row_ptr) {
  if (blockIdx.x < 10) {
    int n = blockIdx.x * 1024 + threadIdx.x;
    if (n < NN) {
      int a = deg_src[n]; if (a < 1) a = 1;
      int b = deg_dst[n]; if (b < 1) b = 1;
      dsrc[n] = 1.0f / sqrtf((float)a);
      ddst[n] = 1.0f / sqrtf((float)b);
      if (n == 0) gstart[gid[0]] = 0;
      else if (gid[n] != gid[n - 1]) gstart[gid[n]] = n;
      if (n == NN - 1) gstart[GG] = NN;
    }
    return;
  }
  // single-pass parallel scan: thread t owns degrees [t*10, t*10+10)
  __shared__ int wsum[16];
  int t = threadIdx.x, lane = t & 63, wid = t >> 6;
  int base = t * 10;
  int loc[10];
  int s = 0;
#pragma unroll
  for (int i = 0; i < 10; i++) {
    int idx = base + i;
    int v = (idx < NN) ? deg_dst[idx] : 0;
    s += v;
    loc[i] = s;  // inclusive prefix within thread
  }
  int x = s;
#pragma unroll
  for (int off = 1; off < 64; off <<= 1) {
    int u = __shfl_up(x, off);
    if (lane >= off) x += u;
  }
  if (lane == 63) wsum[wid] = x;
  __syncthreads();
  if (wid == 0 && lane < 16) {
    int y = wsum[lane];
#pragma unroll
    for (int off = 1; off < 16; off <<= 1) {
      int u = __shfl_up(y, off, 16);
      if (lane >= off) y += u;
    }
    wsum[lane] = y;
  }
  __syncthreads();
  int woff = (wid > 0) ? wsum[wid - 1] : 0;
  int ex = woff + x - s;  // exclusive prefix of this thread's range
  if (t == 0) row_ptr[0] = 0;
#pragma unroll
  for (int i = 0; i < 10; i++) {
    int idx = base + i;
    if (idx < NN) row_ptr[idx + 1] = ex + loc[i];
  }
}

__global__ __launch_bounds__(64) void sort_rows_kernel(const int* __restrict__ row_ptr,
                                                       int* csr_src) {
  int n = blockIdx.x;
  int s0 = row_ptr[n];
  int L = row_ptr[n + 1] - s0;
  if (L <= 1) return;
  __shared__ int buf[512];
  if (L <= 512) {
    for (int i = threadIdx.x; i < L; i += 64) buf[i] = csr_src[s0 + i];
    __syncthreads();
    for (int i = threadIdx.x; i < L; i += 64) {
      int v = buf[i], r = 0;
      for (int j = 0; j < L; j++) {
        int u = buf[j];
        r += (u < v) || (u == v && j < i);
      }
      csr_src[s0 + r] = v;
    }
  } else if (threadIdx.x == 0) {
    for (int i = s0 + 1; i < s0 + L; i++) {
      int v = csr_src[i], j = i - 1;
      while (j >= s0 && csr_src[j] > v) { csr_src[j + 1] = csr_src[j]; j--; }
      csr_src[j + 1] = v;
    }
  }
}

// =================== device helpers ===================

__device__ inline void dev_gcn_agg(int n, int lane,
    const u16* __restrict__ xb, const float* __restrict__ dsrc, const float* __restrict__ ddst,
    const int* __restrict__ row_ptr, const int* __restrict__ csr_src,
    u16* __restrict__ out, int F) {
  int s0 = row_ptr[n], s1 = row_ptr[n + 1];
  float dd = ddst[n];
  if (F == 256) {
    int bf = lane * 4;
    float a0 = 0, a1 = 0, a2 = 0, a3 = 0;
    int e = s0;
    for (; e + 1 < s1; e += 2) {
      int sA = csr_src[e], sB = csr_src[e + 1];
      float wA = dsrc[sA], wB = dsrc[sB];
      uint2 vA = *(const uint2*)&xb[(size_t)sA * 256 + bf];
      uint2 vB = *(const uint2*)&xb[(size_t)sB * 256 + bf];
      a0 += wA * bflo(vA.x) + wB * bflo(vB.x);
      a1 += wA * bfhi(vA.x) + wB * bfhi(vB.x);
      a2 += wA * bflo(vA.y) + wB * bflo(vB.y);
      a3 += wA * bfhi(vA.y) + wB * bfhi(vB.y);
    }
    if (e < s1) {
      int s = csr_src[e];
      float w = dsrc[s];
      uint2 v = *(const uint2*)&xb[(size_t)s * 256 + bf];
      a0 += w * bflo(v.x); a1 += w * bfhi(v.x);
      a2 += w * bflo(v.y); a3 += w * bfhi(v.y);
    }
    ushort4 o;
    o.x = f2bf(a0 * dd); o.y = f2bf(a1 * dd); o.z = f2bf(a2 * dd); o.w = f2bf(a3 * dd);
    *(ushort4*)&out[(size_t)n * 256 + bf] = o;
  } else {  // F == 128
    int bf = lane * 2;
    float a0 = 0, a1 = 0;
    int e = s0;
    for (; e + 1 < s1; e += 2) {
      int sA = csr_src[e], sB = csr_src[e + 1];
      float wA = dsrc[sA], wB = dsrc[sB];
      unsigned vA = *(const unsigned*)&xb[(size_t)sA * 128 + bf];
      unsigned vB = *(const unsigned*)&xb[(size_t)sB * 128 + bf];
      a0 += wA * bflo(vA) + wB * bflo(vB);
      a1 += wA * bfhi(vA) + wB * bfhi(vB);
    }
    if (e < s1) {
      int s = csr_src[e];
      float w = dsrc[s];
      unsigned v = *(const unsigned*)&xb[(size_t)s * 128 + bf];
      a0 += w * bflo(v); a1 += w * bfhi(v);
    }
    ushort2 o;
    o.x = f2bf(a0 * dd); o.y = f2bf(a1 * dd);
    *(ushort2*)&out[(size_t)n * 128 + bf] = o;
  }
}

__device__ inline void dev_scores(int n, int lane, const float* __restrict__ x,
                                  const float* __restrict__ wl, const float* __restrict__ wr,
                                  float* __restrict__ asrc, float* __restrict__ adst, int K) {
  float a0 = 0, a1 = 0, b0 = 0, b1 = 0;
  for (int k = lane; k < K; k += 64) {
    float xv = x[(size_t)n * K + k];
    a0 += xv * wl[k];
    a1 += xv * wl[K + k];
    b0 += xv * wr[k];
    b1 += xv * wr[K + k];
  }
#pragma unroll
  for (int off = 32; off; off >>= 1) {
    a0 += __shfl_down(a0, off);
    a1 += __shfl_down(a1, off);
    b0 += __shfl_down(b0, off);
    b1 += __shfl_down(b1, off);
  }
  if (lane == 0) {
    asrc[n * 2 + 0] = a0; asrc[n * 2 + 1] = a1;
    adst[n * 2 + 0] = b0; adst[n * 2 + 1] = b1;
  }
}

__device__ inline void dev_scores_bf(int n, int lane, const u16* __restrict__ xb,
                                     const float* __restrict__ wl, const float* __restrict__ wr,
                                     float* __restrict__ asrc, float* __restrict__ adst) {
  float a0 = 0, a1 = 0, b0 = 0, b1 = 0;
#pragma unroll
  for (int idx = lane; idx < 128; idx += 64) {
    unsigned v = *(const unsigned*)&xb[(size_t)n * 256 + idx * 2];
    float lo = bflo(v), hi = bfhi(v);
    a0 += lo * wl[idx * 2] + hi * wl[idx * 2 + 1];
    a1 += lo * wl[256 + idx * 2] + hi * wl[256 + idx * 2 + 1];
    b0 += lo * wr[idx * 2] + hi * wr[idx * 2 + 1];
    b1 += lo * wr[256 + idx * 2] + hi * wr[256 + idx * 2 + 1];
  }
#pragma unroll
  for (int off = 32; off; off >>= 1) {
    a0 += __shfl_down(a0, off);
    a1 += __shfl_down(a1, off);
    b0 += __shfl_down(b0, off);
    b1 += __shfl_down(b1, off);
  }
  if (lane == 0) {
    asrc[n * 2 + 0] = a0; asrc[n * 2 + 1] = a1;
    adst[n * 2 + 0] = b0; adst[n * 2 + 1] = b1;
  }
}

// fused edge-softmax + x-space aggregation, 4 nodes/block, wave per node.
template<int F>
__device__ inline void dev_gatfuse_v3(int n0, int tid,
    const u16* __restrict__ xb,
    const float* __restrict__ asrc, const float* __restrict__ adst,
    const int* __restrict__ row_ptr, const int* __restrict__ csr_src,
    u16* __restrict__ gx, SmemFuseV2& sf) {
  int w = tid >> 6, lane = tid & 63;
  {
    int n = n0 + w;
    int s0 = row_ptr[n];
    int deg = row_ptr[n + 1] - s0;
    float2 an = *(const float2*)&adst[n * 2];
    float m0 = -INFINITY, m1 = -INFINITY;
    if (deg <= MAXDEG) {
      for (int i = lane; i < deg; i += 64) {
        int s = csr_src[s0 + i];
        sf.idx[w][i] = s;
        float2 as = *(const float2*)&asrc[s * 2];
        float e0 = as.x + an.x; e0 = (e0 > 0.f) ? e0 : 0.2f * e0;
        float e1 = as.y + an.y; e1 = (e1 > 0.f) ? e1 : 0.2f * e1;
        sf.al[w][0][i] = e0; sf.al[w][1][i] = e1;
        m0 = fmaxf(m0, e0); m1 = fmaxf(m1, e1);
      }
#pragma unroll
      for (int off = 32; off; off >>= 1) {
        m0 = fmaxf(m0, __shfl_xor(m0, off));
        m1 = fmaxf(m1, __shfl_xor(m1, off));
      }
      float t0 = 0.f, t1 = 0.f;
      for (int i = lane; i < deg; i += 64) {
        float w0 = __expf(sf.al[w][0][i] - m0);
        float w1 = __expf(sf.al[w][1][i] - m1);
        sf.al[w][0][i] = w0; sf.al[w][1][i] = w1;
        t0 += w0; t1 += w1;
      }
#pragma unroll
      for (int off = 32; off; off >>= 1) {
        t0 += __shfl_xor(t0, off);
        t1 += __shfl_xor(t1, off);
      }
      if (lane == 0) {
        sf.inv[w][0] = (t0 > 0.f) ? 1.f / t0 : 0.f;
        sf.inv[w][1] = (t1 > 0.f) ? 1.f / t1 : 0.f;
      }
    } else {
      for (int i = lane; i < deg; i += 64) {
        float2 as = *(const float2*)&asrc[csr_src[s0 + i] * 2];
        float e0 = as.x + an.x; e0 = (e0 > 0.f) ? e0 : 0.2f * e0;
        float e1 = as.y + an.y; e1 = (e1 > 0.f) ? e1 : 0.2f * e1;
        m0 = fmaxf(m0, e0); m1 = fmaxf(m1, e1);
      }
#pragma unroll
      for (int off = 32; off; off >>= 1) {
        m0 = fmaxf(m0, __shfl_xor(m0, off));
        m1 = fmaxf(m1, __shfl_xor(m1, off));
      }
      float t0 = 0.f, t1 = 0.f;
      for (int i = lane; i < deg; i += 64) {
        float2 as = *(const float2*)&asrc[csr_src[s0 + i] * 2];
        float e0 = as.x + an.x; e0 = (e0 > 0.f) ? e0 : 0.2f * e0;
        float e1 = as.y + an.y; e1 = (e1 > 0.f) ? e1 : 0.2f * e1;
        t0 += __expf(e0 - m0); t1 += __expf(e1 - m1);
      }
#pragma unroll
      for (int off = 32; off; off >>= 1) {
        t0 += __shfl_xor(t0, off);
        t1 += __shfl_xor(t1, off);
      }
      if (lane == 0) {
        sf.inv[w][0] = (t0 > 0.f) ? 1.f / t0 : 0.f;
        sf.inv[w][1] = (t1 > 0.f) ? 1.f / t1 : 0.f;
        sf.mm[w][0] = m0; sf.mm[w][1] = m1;
      }
    }
  }
  __syncthreads();
  int slot = w;
  int p = lane;
  int n = n0 + slot;
  int s0 = row_ptr[n];
  int deg = row_ptr[n + 1] - s0;
  float i0 = sf.inv[slot][0], i1 = sf.inv[slot][1];
  if (F == 256) {
    float a0[4] = {0, 0, 0, 0}, a1[4] = {0, 0, 0, 0};
    if (deg <= MAXDEG) {
      int i = 0;
      for (; i + 1 < deg; i += 2) {
        int sA = sf.idx[slot][i], sB = sf.idx[slot][i + 1];
        float wA0 = sf.al[slot][0][i] * i0, wA1 = sf.al[slot][1][i] * i1;
        float wB0 = sf.al[slot][0][i + 1] * i0, wB1 = sf.al[slot][1][i + 1] * i1;
        uint2 vA = *(const uint2*)&xb[(size_t)sA * 256 + p * 4];
        uint2 vB = *(const uint2*)&xb[(size_t)sB * 256 + p * 4];
        float fA[4] = {bflo(vA.x), bfhi(vA.x), bflo(vA.y), bfhi(vA.y)};
        float fB[4] = {bflo(vB.x), bfhi(vB.x), bflo(vB.y), bfhi(vB.y)};
#pragma unroll
        for (int j = 0; j < 4; j++) {
          a0[j] += wA0 * fA[j] + wB0 * fB[j];
          a1[j] += wA1 * fA[j] + wB1 * fB[j];
        }
      }
      if (i < deg) {
        int s = sf.idx[slot][i];
        float w0 = sf.al[slot][0][i] * i0, w1 = sf.al[slot][1][i] * i1;
        uint2 v = *(const uint2*)&xb[(size_t)s * 256 + p * 4];
        float fv[4] = {bflo(v.x), bfhi(v.x), bflo(v.y), bfhi(v.y)};
#pragma unroll
        for (int j = 0; j < 4; j++) {
          a0[j] += w0 * fv[j];
          a1[j] += w1 * fv[j];
        }
      }
    } else {
      float mh0 = sf.mm[slot][0], mh1 = sf.mm[slot][1];
      float2 an = *(const float2*)&adst[n * 2];
      for (int i = 0; i < deg; i++) {
        int s = csr_src[s0 + i];
        float2 as = *(const float2*)&asrc[s * 2];
        float e0 = as.x + an.x; e0 = (e0 > 0.f) ? e0 : 0.2f * e0;
        float e1 = as.y + an.y; e1 = (e1 > 0.f) ? e1 : 0.2f * e1;
        float w0 = __expf(e0 - mh0) * i0, w1 = __expf(e1 - mh1) * i1;
        uint2 v = *(const uint2*)&xb[(size_t)s * 256 + p * 4];
        float fv[4] = {bflo(v.x), bfhi(v.x), bflo(v.y), bfhi(v.y)};
#pragma unroll
        for (int j = 0; j < 4; j++) {
          a0[j] += w0 * fv[j];
          a1[j] += w1 * fv[j];
        }
      }
    }
    ushort4 o0, o1;
    o0.x = f2bf(a0[0]); o0.y = f2bf(a0[1]); o0.z = f2bf(a0[2]); o0.w = f2bf(a0[3]);
    o1.x = f2bf(a1[0]); o1.y = f2bf(a1[1]); o1.z = f2bf(a1[2]); o1.w = f2bf(a1[3]);
    *(ushort4*)&gx[(size_t)n * 512 + p * 4] = o0;
    *(ushort4*)&gx[(size_t)n * 512 + 256 + p * 4] = o1;
  } else {  // F == 128
    float a00 = 0.f, a01 = 0.f, a10 = 0.f, a11 = 0.f;
    if (deg <= MAXDEG) {
      int i = 0;
      for (; i + 1 < deg; i += 2) {
        int sA = sf.idx[slot][i], sB = sf.idx[slot][i + 1];
        float wA0 = sf.al[slot][0][i] * i0, wA1 = sf.al[slot][1][i] * i1;
        float wB0 = sf.al[slot][0][i + 1] * i0, wB1 = sf.al[slot][1][i + 1] * i1;
        unsigned vA = *(const unsigned*)&xb[(size_t)sA * 128 + p * 2];
        unsigned vB = *(const unsigned*)&xb[(size_t)sB * 128 + p * 2];
        float lA = bflo(vA), hA = bfhi(vA), lB = bflo(vB), hB = bfhi(vB);
        a00 += wA0 * lA + wB0 * lB; a01 += wA0 * hA + wB0 * hB;
        a10 += wA1 * lA + wB1 * lB; a11 += wA1 * hA + wB1 * hB;
      }
      if (i < deg) {
        int s = sf.idx[slot][i];
        float w0 = sf.al[slot][0][i] * i0, w1 = sf.al[slot][1][i] * i1;
        unsigned v = *(const unsigned*)&xb[(size_t)s * 128 + p * 2];
        float lo = bflo(v), hi = bfhi(v);
        a00 += w0 * lo; a01 += w0 * hi;
        a10 += w1 * lo; a11 += w1 * hi;
      }
    } else {
      float mh0 = sf.mm[slot][0], mh1 = sf.mm[slot][1];
      float2 an = *(const float2*)&adst[n * 2];
      for (int i = 0; i < deg; i++) {
        int s = csr_src[s0 + i];
        float2 as = *(const float2*)&asrc[s * 2];
        float e0 = as.x + an.x; e0 = (e0 > 0.f) ? e0 : 0.2f * e0;
        float e1 = as.y + an.y; e1 = (e1 > 0.f) ? e1 : 0.2f * e1;
        float w0 = __expf(e0 - mh0) * i0, w1 = __expf(e1 - mh1) * i1;
        unsigned v = *(const unsigned*)&xb[(size_t)s * 128 + p * 2];
        float lo = bflo(v), hi = bfhi(v);
        a00 += w0 * lo; a01 += w0 * hi;
        a10 += w1 * lo; a11 += w1 * hi;
      }
    }
    ushort2 o0; o0.x = f2bf(a00); o0.y = f2bf(a01);
    ushort2 o1; o1.x = f2bf(a10); o1.y = f2bf(a11);
    *(ushort2*)&gx[(size_t)n * 256 + p * 2] = o0;
    *(ushort2*)&gx[(size_t)n * 256 + 128 + p * 2] = o1;
  }
}

__device__ inline void dev_gemm(const u16* __restrict__ A, const u16* __restrict__ Wt,
                                const float* __restrict__ bias, u16* __restrict__ Cb,
                                int K, int Nc, int relu, int bx, int by, int tid,
                                SmemGemm& sm) {
  int lane = tid & 63;
  int wid = tid >> 6;
  int wm = wid & 1, wn = wid >> 1;
  int l15 = lane & 15, lg = lane >> 4;
  int row0 = bx * BM;
  int col0 = by * BN;
  f32x4 acc[4][2] = {};
  for (int k0 = 0; k0 < K; k0 += BK) {
#pragma unroll
    for (int p = 0; p < 4; p++) {
      int c = p * 256 + tid;
      int r = c >> 3, k8 = c & 7;
      uint4 v = make_uint4(0, 0, 0, 0);
      int gr = row0 + r;
      if (gr < NN) v = *(const uint4*)&A[(size_t)gr * K + k0 + k8 * 8];
      *(uint4*)&sm.As[r][k8 * 8] = v;
    }
#pragma unroll
    for (int p = 0; p < 2; p++) {
      int c = p * 256 + tid;
      int r = c >> 3, k8 = c & 7;
      uint4 v = *(const uint4*)&Wt[(size_t)(col0 + r) * K + k0 + k8 * 8];
      *(uint4*)&sm.Bs[r][k8 * 8] = v;
    }
    __syncthreads();
#pragma unroll
    for (int ks = 0; ks < BK; ks += 32) {
      bf16x8 afr[4], bfr[2];
#pragma unroll
      for (int m = 0; m < 4; m++)
        afr[m] = *(const bf16x8*)&sm.As[wm * 64 + m * 16 + l15][ks + lg * 8];
#pragma unroll
      for (int nn = 0; nn < 2; nn++)
        bfr[nn] = *(const bf16x8*)&sm.Bs[wn * 32 + nn * 16 + l15][ks + lg * 8];
#pragma unroll
      for (int m = 0; m < 4; m++)
#pragma unroll
        for (int nn = 0; nn < 2; nn++)
          acc[m][nn] = __builtin_amdgcn_mfma_f32_16x16x32_bf16(afr[m], bfr[nn], acc[m][nn], 0, 0, 0);
    }
    __syncthreads();
  }
#pragma unroll
  for (int m = 0; m < 4; m++) {
#pragma unroll
    for (int nn = 0; nn < 2; nn++) {
      int gc = col0 + wn * 32 + nn * 16 + l15;
      float bv = bias ? bias[gc] : 0.f;
#pragma unroll
      for (int j = 0; j < 4; j++) {
        int gr = row0 + wm * 64 + m * 16 + lg * 4 + j;
        if (gr < NN) {
          float v = acc[m][nn][j] + bv;
          if (relu) v = fmaxf(v, 0.f);
          Cb[(size_t)gr * Nc + gc] = f2bf(v);
        }
      }
    }
  }
}

__device__ inline void dev_gat_gemm(const u16* __restrict__ gx, const u16* __restrict__ Wt,
                                    const float* __restrict__ bias, u16* __restrict__ gb,
                                    int K, int bx, int by, int tid, SmemGatGemm& sm) {
  int lane = tid & 63;
  int wid = tid >> 6;
  int wm = wid & 1, wn = wid >> 1;
  int l15 = lane & 15, lg = lane >> 4;
  int row0 = bx * 64;
  int col0 = by * 64;
  int str = 2 * K;
  f32x4 acc[2][2][2] = {};
  for (int k0 = 0; k0 < K; k0 += BK) {
#pragma unroll
    for (int hh = 0; hh < 2; hh++) {
#pragma unroll
      for (int p = 0; p < 2; p++) {
        int c = p * 256 + tid;
        int r = c >> 3, k8 = c & 7;
        int gr = row0 + r;
        uint4 v = make_uint4(0, 0, 0, 0);
        if (gr < NN) v = *(const uint4*)&gx[(size_t)gr * str + hh * K + k0 + k8 * 8];
        *(uint4*)&sm.A[hh][r][k8 * 8] = v;
      }
#pragma unroll
      for (int p = 0; p < 2; p++) {
        int c = p * 256 + tid;
        int r = c >> 3, k8 = c & 7;
        uint4 v = *(const uint4*)&Wt[(size_t)(hh * 256 + col0 + r) * K + k0 + k8 * 8];
        *(uint4*)&sm.B[hh][r][k8 * 8] = v;
      }
    }
    __syncthreads();
#pragma unroll
    for (int ks = 0; ks < BK; ks += 32) {
      bf16x8 af[2][2], bf_[2][2];
#pragma unroll
      for (int hh = 0; hh < 2; hh++) {
#pragma unroll
        for (int m = 0; m < 2; m++)
          af[hh][m] = *(const bf16x8*)&sm.A[hh][wm * 32 + m * 16 + l15][ks + lg * 8];
#pragma unroll
        for (int nn = 0; nn < 2; nn++)
          bf_[hh][nn] = *(const bf16x8*)&sm.B[hh][wn * 32 + nn * 16 + l15][ks + lg * 8];
      }
#pragma unroll
      for (int hh = 0; hh < 2; hh++)
#pragma unroll
        for (int m = 0; m < 2; m++)
#pragma unroll
          for (int nn = 0; nn < 2; nn++)
            acc[hh][m][nn] = __builtin_amdgcn_mfma_f32_16x16x32_bf16(af[hh][m], bf_[hh][nn], acc[hh][m][nn], 0, 0, 0);
    }
    __syncthreads();
  }
#pragma unroll
  for (int m = 0; m < 2; m++) {
#pragma unroll
    for (int nn = 0; nn < 2; nn++) {
      int gc = col0 + wn * 32 + nn * 16 + l15;
      float bv0 = bias[gc], bv1 = bias[256 + gc];
#pragma unroll
      for (int j = 0; j < 4; j++) {
        int gr = row0 + wm * 32 + m * 16 + lg * 4 + j;
        if (gr < NN) {
          float r0 = fmaxf(acc[0][m][nn][j] + bv0, 0.f);
          float r1 = fmaxf(acc[1][m][nn][j] + bv1, 0.f);
          gb[(size_t)gr * 256 + gc] = f2bf(0.5f * (r0 + r1));
        }
      }
    }
  }
}

__device__ inline void dev_stage1(const u16* __restrict__ x, int l, int g, int s, int f,
                                  const int* __restrict__ gstart, float* __restrict__ partial) {
  int n0 = gstart[g], n1 = gstart[g + 1];
  int cnt = n1 - n0;
  int chunk = (cnt + RS - 1) / RS;
  int a = n0 + s * chunk;
  int bnd = a + chunk; if (bnd > n1) bnd = n1;
  float sum = 0.f, mx = -INFINITY;
  for (int n = a; n < bnd; n++) {
    float v = bf2f(x[(size_t)n * HH + f]);
    sum += v;
    mx = fmaxf(mx, v);
  }
  size_t base = ((size_t)l * GG * RS + g * RS + s) * 2 * HH;
  partial[base + f] = sum;
  partial[base + HH + f] = mx;
}

__device__ inline float dev_stage2_val(const float* __restrict__ partial, int l, int g, int tt,
                                       const int* __restrict__ gstart) {
  int f = tt & 255, ismax = tt >> 8;
  size_t base = ((size_t)l * GG * RS + g * RS) * 2 * HH;
  if (!ismax) {
    float s = 0.f;
    for (int k = 0; k < RS; k++) s += partial[base + (size_t)k * 2 * HH + f];
    return s / (float)(gstart[g + 1] - gstart[g]);
  } else {
    float m = -INFINITY;
    for (int k = 0; k < RS; k++) m = fmaxf(m, partial[base + (size_t)k * 2 * HH + HH + f]);
    return m;
  }
}

// =================== stage kernels ===================

// fill_csr [0,625) + scores1 (fp32 h) [625,3125)
__global__ __launch_bounds__(256) void k_fill_scores(
    const int* __restrict__ src, const int* __restrict__ dst,
    const int* __restrict__ row_ptr, int* fill, int* csr_src,
    const float* __restrict__ h, const float* __restrict__ wl1, const float* __restrict__ wr1,
    float* __restrict__ asrc, float* __restrict__ adst) {
  int b = blockIdx.x, t = threadIdx.x;
  if (b < 625) {
    int e = b * 256 + t;
    if (e < EE) {
      int d = dst[e];
      int p = atomicAdd(&fill[d], 1);
      csr_src[row_ptr[d] + p] = src[e];
    }
  } else {
    int n = (b - 625) * 4 + (t >> 6);
    if (n < NN) dev_scores(n, t & 63, h, wl1, wr1, asrc, adst, FIN);
  }
}

// gcn_agg1(F=128) [0,2500) + gatfuse1<128> [2500,5000)
__global__ __launch_bounds__(256) void k_a1(
    const u16* __restrict__ h_bf, const float* __restrict__ dsrc, const float* __restrict__ ddst,
    const int* __restrict__ row_ptr, const int* __restrict__ csr_src,
    u16* __restrict__ zagg, const float* __restrict__ asrc, const float* __restrict__ adst,
    u16* __restrict__ gx) {
  __shared__ SmemFuseV2 sf;
  int b = blockIdx.x, t = threadIdx.x;
  if (b < 2500) {
    int n = b * 4 + (t >> 6);
    dev_gcn_agg(n, t & 63, h_bf, dsrc, ddst, row_ptr, csr_src, zagg, FIN);
  } else {
    dev_gatfuse_v3<128>((b - 2500) * 4, t, h_bf, asrc, adst, row_ptr, csr_src, gx, sf);
  }
}

// gcn GEMM [0,316) + gat GEMM [316,944)
__global__ __launch_bounds__(256) void k_b(
    const u16* __restrict__ zagg, const u16* __restrict__ gcn_Wt, const float* __restrict__ gcn_b,
    u16* __restrict__ ab_out, int Kg,
    const u16* __restrict__ gx, const u16* __restrict__ gat_Wt, const float* __restrict__ gat_b,
    u16* __restrict__ gb_out, int Ka) {
  __shared__ union { SmemGemm g; SmemGatGemm gg; } sm;
  int b = blockIdx.x, t = threadIdx.x;
  if (b < 316) {
    dev_gemm(zagg, gcn_Wt, gcn_b, ab_out, Kg, HH, 1, b % 79, b / 79, t, sm.g);
  } else {
    int i = b - 316;
    dev_gat_gemm(gx, gat_Wt, gat_b, gb_out, Ka, i / 4, i % 4, t, sm.gg);
  }
}

// scores only (2500 blocks, 4 nodes each)
__global__ __launch_bounds__(256) void k_sc(
    const u16* __restrict__ gb_prev, const float* __restrict__ wl, const float* __restrict__ wr,
    float* __restrict__ asrc, float* __restrict__ adst) {
  int n = blockIdx.x * 4 + (threadIdx.x >> 6);
  dev_scores_bf(n, threadIdx.x & 63, gb_prev, wl, wr, asrc, adst);
}

// gcn_agg(F=256) [0,2500) + gatfuse<256> [2500,5000)
__global__ __launch_bounds__(256) void k_af(
    const u16* __restrict__ ab_prev, const float* __restrict__ dsrc, const float* __restrict__ ddst,
    const int* __restrict__ row_ptr, const int* __restrict__ csr_src, u16* __restrict__ zagg,
    const u16* __restrict__ gb_prev, const float* __restrict__ asrc, const float* __restrict__ adst,
    u16* __restrict__ gx) {
  __shared__ SmemFuseV2 sf;
  int b = blockIdx.x, t = threadIdx.x;
  if (b < 2500) {
    int n = b * 4 + (t >> 6);
    dev_gcn_agg(n, t & 63, ab_prev, dsrc, ddst, row_ptr, csr_src, zagg, HH);
  } else {
    dev_gatfuse_v3<256>((b - 2500) * 4, t, gb_prev, asrc, adst, row_ptr, csr_src, gx, sf);
  }
}

// layer3: gcn_agg [0,2500) + gatfuse<256> [2500,5000) + stage1(ab1->l0,ab2->l1,gb2->l3) [5000,6536)
struct Acts3 { const u16* a[3]; };
__global__ __launch_bounds__(256) void k_af3(
    const u16* __restrict__ ab_prev, const float* __restrict__ dsrc, const float* __restrict__ ddst,
    const int* __restrict__ row_ptr, const int* __restrict__ csr_src, u16* __restrict__ zagg,
    const u16* __restrict__ gb_prev, const float* __restrict__ asrc, const float* __restrict__ adst,
    u16* __restrict__ gx,
    Acts3 acts, const int* __restrict__ gstart, float* __restrict__ partial) {
  __shared__ SmemFuseV2 sf;
  int b = blockIdx.x, t = threadIdx.x;
  if (b < 2500) {
    int n = b * 4 + (t >> 6);
    dev_gcn_agg(n, t & 63, ab_prev, dsrc, ddst, row_ptr, csr_src, zagg, HH);
  } else if (b < 5000) {
    dev_gatfuse_v3<256>((b - 2500) * 4, t, gb_prev, asrc, adst, row_ptr, csr_src, gx, sf);
  } else {
    int i = b - 5000;
    int li = i >> 9, rem = i & 511;
    int lmap[3] = {0, 1, 3};
    dev_stage1(acts.a[li], lmap[li], rem >> 3, rem & 7, t, gstart, partial);
  }
}

// stage1(ab3->l2, gb3->l4) (1024 blocks)
__global__ __launch_bounds__(256) void k_r(
    const u16* __restrict__ ab3, const u16* __restrict__ gb3,
    const int* __restrict__ gstart, float* __restrict__ partial) {
  int b = blockIdx.x, t = threadIdx.x;
  const u16* x = (b < 512) ? ab3 : gb3;
  int l = (b < 512) ? 2 : 4;
  int i = b & 511;
  dev_stage1(x, l, i >> 3, i & 7, t, gstart, partial);
}

// fc head: all stage2 in-register + assemble + fc
__global__ __launch_bounds__(512) void k_fc(
    const float* __restrict__ partial, const int* __restrict__ gstart,
    const float* __restrict__ W1, const float* __restrict__ b1,
    const float* __restrict__ W2, const float* __restrict__ b2, float* __restrict__ out) {
  int g = blockIdx.x;
  int t = threadIdx.x;
  __shared__ float row[1024];
  __shared__ float f1[128];
  {
    int c = t;
    float s0 = dev_stage2_val(partial, 0, g, c, gstart);
    float s1 = dev_stage2_val(partial, 1, g, c, gstart);
    float s2 = dev_stage2_val(partial, 2, g, c, gstart);
    float s3v = dev_stage2_val(partial, 3, g, c, gstart);
    float spec = s0 + s1 + s2;
    float last = (c < 256) ? s3v : dev_stage2_val(partial, 4, g, c, gstart);
    float spat = s0 + s3v + last;
    row[c] = spec;
    row[512 + c] = spat;
  }
  __syncthreads();
  if (t < 128) {
    float acc = b1[t];
    for (int k = 0; k < 1024; k++) acc += row[k] * W1[k * 128 + t];
    f1[t] = fmaxf(acc, 0.f);
  }
  __syncthreads();
  if (t < 2) {
    float a = b2[t];
    for (int k = 0; k < 128; k++) a += f1[k] * W2[k * 2 + t];
    out[g * 2 + t] = 1.f / (1.f + expf(-a));
  }
}

extern "C" void kernel_launch(void* const* d_in, const int* in_sizes, int n_in,
                              void* d_out, int out_size, void* d_ws, size_t ws_size,
                              hipStream_t stream) {
  const float* h      = (const float*)d_in[0];
  const int*   src    = (const int*)d_in[1];
  const int*   dst    = (const int*)d_in[2];
  const int*   gid    = (const int*)d_in[3];
  const float* gcn1_W = (const float*)d_in[4];  const float* gcn1_b = (const float*)d_in[5];
  const float* gcn2_W = (const float*)d_in[6];  const float* gcn2_b = (const float*)d_in[7];
  const float* gcn3_W = (const float*)d_in[8];  const float* gcn3_b = (const float*)d_in[9];
  const float* gat1_W = (const float*)d_in[10]; const float* gat1_al = (const float*)d_in[11];
  const float* gat1_ar= (const float*)d_in[12]; const float* gat1_b = (const float*)d_in[13];
  const float* gat2_W = (const float*)d_in[14]; const float* gat2_al = (const float*)d_in[15];
  const float* gat2_ar= (const float*)d_in[16]; const float* gat2_b = (const float*)d_in[17];
  const float* gat3_W = (const float*)d_in[18]; const float* gat3_al = (const float*)d_in[19];
  const float* gat3_ar= (const float*)d_in[20]; const float* gat3_b = (const float*)d_in[21];
  const float* fc1_W  = (const float*)d_in[22]; const float* fc1_b = (const float*)d_in[23];
  const float* fc2_W  = (const float*)d_in[24]; const float* fc2_b = (const float*)d_in[25];

  char* ws = (char*)d_ws;
  size_t off = 0;
  auto alloc = [&](size_t bytes) -> void* {
    void* p = ws + off;
    off += (bytes + 255) & ~(size_t)255;
    return p;
  };
  u16*   gx      = (u16*)alloc((size_t)NN * ZW * 2);
  u16*   Zagg    = (u16*)alloc((size_t)NN * HH * 2);
  u16*   h_bf    = (u16*)alloc((size_t)NN * FIN * 2);
  u16*   ab1     = (u16*)alloc((size_t)NN * HH * 2);
  u16*   ab2     = (u16*)alloc((size_t)NN * HH * 2);
  u16*   ab3     = (u16*)alloc((size_t)NN * HH * 2);
  u16*   gb1     = (u16*)alloc((size_t)NN * HH * 2);
  u16*   gb2     = (u16*)alloc((size_t)NN * HH * 2);
  u16*   gb3     = (u16*)alloc((size_t)NN * HH * 2);
  int*   row_ptr = (int*)alloc((NN + 1) * 4);
  int*   csr_src = (int*)alloc((size_t)EE * 4);
  int*   meta    = (int*)alloc((size_t)3 * NN * 4);
  int*   deg_src = meta;
  int*   deg_dst = meta + NN;
  int*   fill    = meta + 2 * NN;
  float* dsrc    = (float*)alloc(NN * 4);
  float* ddst    = (float*)alloc(NN * 4);
  int*   gstart  = (int*)alloc((GG + 1) * 4);
  float* asrc    = (float*)alloc(NN * 2 * 4);
  float* adst    = (float*)alloc(NN * 2 * 4);
  float* wl1     = (float*)alloc(2 * FIN * 4);
  float* wr1     = (float*)alloc(2 * FIN * 4);
  float* wl2     = (float*)alloc(2 * HH * 4);
  float* wr2     = (float*)alloc(2 * HH * 4);
  float* wl3     = (float*)alloc(2 * HH * 4);
  float* wr3     = (float*)alloc(2 * HH * 4);
  float* partial = (float*)alloc((size_t)5 * GG * RS * 2 * HH * 4);
  u16* gcn1_Wt = (u16*)alloc((size_t)FIN * HH * 2);
  u16* gcn2_Wt = (u16*)alloc((size_t)HH * HH * 2);
  u16* gcn3_Wt = (u16*)alloc((size_t)HH * HH * 2);
  u16* gat1_Wt = (u16*)alloc((size_t)FIN * ZW * 2);
  u16* gat2_Wt = (u16*)alloc((size_t)HH * ZW * 2);
  u16* gat3_Wt = (u16*)alloc((size_t)HH * ZW * 2);

  hipMemsetAsync(meta, 0, (size_t)3 * NN * 4, stream);
  k_count_prep<<<3800, 256, 0, stream>>>(
      src, dst, deg_src, deg_dst,
      gcn1_W, gcn1_Wt, gcn2_W, gcn2_Wt, gcn3_W, gcn3_Wt,
      gat1_W, gat1_Wt, gat2_W, gat2_Wt, gat3_W, gat3_Wt,
      h, h_bf,
      gat1_al, gat1_ar, gat2_al, gat2_ar, gat3_al, gat3_ar,
      wl1, wr1, wl2, wr2, wl3, wr3);
  k_norms_scan<<<11, 1024, 0, stream>>>(deg_src, deg_dst, gid, dsrc, ddst, gstart, row_ptr);
  k_fill_scores<<<3125, 256, 0, stream>>>(src, dst, row_ptr, fill, csr_src,
                                          h, wl1, wr1, asrc, adst);
  sort_rows_kernel<<<NN, 64, 0, stream>>>(row_ptr, csr_src);

  // layer 1
  k_a1<<<5000, 256, 0, stream>>>(h_bf, dsrc, ddst, row_ptr, csr_src, Zagg, asrc, adst, gx);
  k_b<<<944, 256, 0, stream>>>(Zagg, gcn1_Wt, gcn1_b, ab1, FIN,
                               gx, gat1_Wt, gat1_b, gb1, FIN);
  // layer 2
  k_sc<<<2500, 256, 0, stream>>>(gb1, wl2, wr2, asrc, adst);
  k_af<<<5000, 256, 0, stream>>>(ab1, dsrc, ddst, row_ptr, csr_src, Zagg,
                                 gb1, asrc, adst, gx);
  k_b<<<944, 256, 0, stream>>>(Zagg, gcn2_Wt, gcn2_b, ab2, HH,
                               gx, gat2_Wt, gat2_b, gb2, HH);
  // layer 3
  k_sc<<<2500, 256, 0, stream>>>(gb2, wl3, wr3, asrc, adst);
  Acts3 acts; acts.a[0] = ab1; acts.a[1] = ab2; acts.a[2] = gb2;
  k_af3<<<6536, 256, 0, stream>>>(ab2, dsrc, ddst, row_ptr, csr_src, Zagg,
                                  gb2, asrc, adst, gx,
                                  acts, gstart, partial);
  k_b<<<944, 256, 0, stream>>>(Zagg, gcn3_Wt, gcn3_b, ab3, HH,
                               gx, gat3_Wt, gat3_b, gb3, HH);
  // readouts + head
  k_r<<<1024, 256, 0, stream>>>(ab3, gb3, gstart, partial);
  k_fc<<<GG, 512, 0, stream>>>(partial, gstart, fc1_W, fc1_b, fc2_W, fc2_b, (float*)d_out);
}